// Round 6
// baseline (335.164 us; speedup 1.0000x reference)
//
#include <hip/hip_runtime.h>
#include <hip/hip_bf16.h>
#include <math.h>
#include <stdint.h>

#define EPSV 1e-5f
#define BCAP 2560        // bucket capacity: mean 2048, sigma ~45 -> 11 sigma slack
#define NBMAX 1024       // >= ceil(N/128)
#define SLOTS 32         // BN-stat partial slots

typedef unsigned int u32x4 __attribute__((ext_vector_type(4)));
typedef float f32x4 __attribute__((ext_vector_type(4)));

static __device__ __forceinline__ float bf_lo(unsigned int u) {
  union { unsigned int i; float f; } v; v.i = u << 16; return v.f;
}
static __device__ __forceinline__ float bf_hi(unsigned int u) {
  union { unsigned int i; float f; } v; v.i = u & 0xffff0000u; return v.f;
}
static __device__ __forceinline__ unsigned short f2bf(float f) {
  union { float f; unsigned int i; } v; v.f = f;
  unsigned int r = v.i + 0x7fff + ((v.i >> 16) & 1);  // RTNE
  return (unsigned short)(r >> 16);
}
// nontemporal helpers: keep streaming traffic out of L2 so the 4MB/XCD L2
// holds more of the gather table (Hs). Use ONLY for sequential streams;
// scattered 4B stores must stay cached for line write-combining.
static __device__ __forceinline__ void nts_u4(void* p, uint4 v) {
  u32x4 w; w[0] = v.x; w[1] = v.y; w[2] = v.z; w[3] = v.w;
  __builtin_nontemporal_store(w, (u32x4*)p);
}
static __device__ __forceinline__ void nts_f4(void* p, float4 v) {
  f32x4 w; w[0] = v.x; w[1] = v.y; w[2] = v.z; w[3] = v.w;
  __builtin_nontemporal_store(w, (f32x4*)p);
}

// ---------------- phase A: bin edges into 128-node buckets ----------------
__global__ __launch_bounds__(256) void k_binA(const int* __restrict__ src,
                                              const int* __restrict__ dst,
                                              int* __restrict__ gcount,
                                              int* __restrict__ staging, int E, int NB) {
  __shared__ int hist[NBMAX];
  __shared__ int gbase[NBMAX];
  int t = threadIdx.x;
  for (int b = t; b < NB; b += 256) hist[b] = 0;
  __syncthreads();
  int e0 = blockIdx.x * 4096;
  int sreg[16], dreg[16];
#pragma unroll
  for (int j = 0; j < 16; j++) {
    int e = e0 + j * 256 + t;
    if (e < E) {
      sreg[j] = __builtin_nontemporal_load(&src[e]);
      dreg[j] = __builtin_nontemporal_load(&dst[e]);
      atomicAdd(&hist[dreg[j] >> 7], 1);
    } else {
      dreg[j] = -1;
    }
  }
  __syncthreads();
  for (int b = t; b < NB; b += 256) {
    int c = hist[b];
    if (c) gbase[b] = b * BCAP + atomicAdd(&gcount[b], c);
    hist[b] = 0;  // reuse as local rank counter
  }
  __syncthreads();
#pragma unroll
  for (int j = 0; j < 16; j++) {
    if (dreg[j] >= 0) {
      int b = dreg[j] >> 7;
      int r = atomicAdd(&hist[b], 1);
      int pos = gbase[b] + r;
      if (pos < (b + 1) * BCAP)  // overflow guard (statistically impossible)
        staging[pos] = sreg[j] | ((dreg[j] & 127) << 20);  // scattered: cached
    }
  }
}

// ---------------- phase B: bucket -> CSR at STATIC base b*BCAP ----------------
__global__ __launch_bounds__(256) void k_binB(const int* __restrict__ staging,
                                              const int* __restrict__ gcount,
                                              int2* __restrict__ rowseg,
                                              float* __restrict__ dinv,
                                              int* __restrict__ edges, int N) {
  __shared__ int rec[BCAP];
  __shared__ int cnt[128], cur[128], scn[128];
  int b = blockIdx.x;
  int t = threadIdx.x;
  int lo = b * 128;
  int nn = min(128, N - lo);
  int c = min(gcount[b], BCAP);
  if (t < 128) cnt[t] = 0;
  __syncthreads();
  for (int r = t; r < c; r += 256) {
    int x = __builtin_nontemporal_load(&staging[b * BCAP + r]);
    rec[r] = x;
    atomicAdd(&cnt[x >> 20], 1);
  }
  __syncthreads();
  if (t < 128) scn[t] = cnt[t];
  __syncthreads();
  for (int off = 1; off < 128; off <<= 1) {
    int tv = (t < 128 && t >= off) ? scn[t - off] : 0;
    __syncthreads();
    if (t < 128 && t >= off) scn[t] += tv;
    __syncthreads();
  }
  int base = b * BCAP;  // static bucket base
  if (t < 128) {
    int excl = (t == 0) ? 0 : scn[t - 1];
    cur[t] = excl;
    if (t < nn) {
      rowseg[lo + t] = make_int2(base + excl, base + excl + cnt[t]);
      dinv[lo + t] = rsqrtf((float)cnt[t] + 1.0f);  // +1 = self loop
    }
  }
  __syncthreads();
  for (int r = t; r < c; r += 256) {
    int x = rec[r];
    int pos = base + atomicAdd(&cur[x >> 20], 1);
    edges[pos] = x & 0xFFFFF;  // scattered: cached
  }
}

// ---------------- GEMM (+ fused BN fold) ----------------
// CSPL=2 for DOUT=64: columns split BY BLOCK PARITY (c0beg is an SGPR value ->
// W[k*DOUT+c0+j] stays wave-uniform -> scalar s_load broadcasts). R2 lesson:
// per-lane column offsets make W loads vector loads (127us disaster).
template <int DOUT, bool BFIN, bool FOLD>
__global__ __launch_bounds__(256) void k_gemm(const void* __restrict__ Xv,
                                              const float* __restrict__ W,
                                              const float* __restrict__ stats,
                                              const float* __restrict__ g,
                                              const float* __restrict__ be,
                                              const float* __restrict__ dinv,
                                              unsigned short* __restrict__ Hs,
                                              float* __restrict__ zstats, int N,
                                              float invN) {
  __shared__ float red[128];
  __shared__ float scale[64], shift[64], browS[64];
  int t = threadIdx.x;
  if (zstats && blockIdx.x == 0) {
    for (int i = t; i < SLOTS * 128; i += 256) zstats[i] = 0.f;
  }
  if constexpr (FOLD) {
    if (t < 128) {
      float s = 0.f;
      for (int b = 0; b < SLOTS; b++) s += stats[(size_t)b * 128 + t];
      red[t] = s;
    }
    __syncthreads();
    if (t < 64) {
      float mean = red[t] * invN;
      float var = red[64 + t] * invN - mean * mean;
      float sc = g[t] * rsqrtf(var + EPSV);
      scale[t] = sc;
      shift[t] = be[t] - mean * sc;
    }
    __syncthreads();
    if (t < DOUT) {
      float a = 0.f;
      for (int k = 0; k < 64; k++) a = fmaf(shift[k], W[k * DOUT + t], a);
      browS[t] = a;
    }
    __syncthreads();
  }
  constexpr int CSPL = (DOUT == 64) ? 2 : 1;
  int bid = blockIdx.x;
  int row = (CSPL == 2 ? (bid >> 1) : bid) * 256 + t;
  int c0beg = (CSPL == 2) ? ((bid & 1) * 32) : 0;  // SGPR -> wave-uniform
  int c0end = c0beg + DOUT / CSPL;
  if (row >= N) return;
  float xs[64];
  if constexpr (BFIN) {
    const u32x4* xp = (const u32x4*)((const unsigned short*)Xv + (size_t)row * 64);
#pragma unroll
    for (int i = 0; i < 8; i++) {
      u32x4 u = __builtin_nontemporal_load(xp + i);  // streamed row: nt
      xs[i * 8 + 0] = bf_lo(u[0]); xs[i * 8 + 1] = bf_hi(u[0]);
      xs[i * 8 + 2] = bf_lo(u[1]); xs[i * 8 + 3] = bf_hi(u[1]);
      xs[i * 8 + 4] = bf_lo(u[2]); xs[i * 8 + 5] = bf_hi(u[2]);
      xs[i * 8 + 6] = bf_lo(u[3]); xs[i * 8 + 7] = bf_hi(u[3]);
    }
  } else {
    const f32x4* xp = (const f32x4*)((const float*)Xv + (size_t)row * 64);
#pragma unroll
    for (int i = 0; i < 16; i++) {
      f32x4 f = __builtin_nontemporal_load(xp + i);  // streamed row: nt
      xs[i * 4 + 0] = f[0]; xs[i * 4 + 1] = f[1];
      xs[i * 4 + 2] = f[2]; xs[i * 4 + 3] = f[3];
    }
  }
  if constexpr (FOLD) {
#pragma unroll
    for (int k = 0; k < 64; k++) xs[k] *= scale[k];  // LDS broadcast, conflict-free
  }
  float di = dinv[row];
#pragma unroll 1
  for (int c0 = c0beg; c0 < c0end; c0 += 8) {
    float acc[8];
#pragma unroll
    for (int j = 0; j < 8; j++) acc[j] = FOLD ? browS[c0 + j] : 0.0f;
#pragma unroll
    for (int k = 0; k < 64; k++) {
      float xk = xs[k];
#pragma unroll
      for (int j = 0; j < 8; j++) acc[j] = fmaf(xk, W[k * DOUT + c0 + j], acc[j]);
    }
    uint4 st;
    st.x = (unsigned int)f2bf(di * acc[0]) | ((unsigned int)f2bf(di * acc[1]) << 16);
    st.y = (unsigned int)f2bf(di * acc[2]) | ((unsigned int)f2bf(di * acc[3]) << 16);
    st.z = (unsigned int)f2bf(di * acc[4]) | ((unsigned int)f2bf(di * acc[5]) << 16);
    st.w = (unsigned int)f2bf(di * acc[6]) | ((unsigned int)f2bf(di * acc[7]) << 16);
    // Hs store stays CACHED: consumed next by agg gathers (cross-kernel L2 reuse)
    *(uint4*)(Hs + (size_t)row * DOUT + c0) = st;
  }
}

// ---------------- gather aggregation: TWO nodes per wave (R1 form) ----------------
// R3 lesson: persistent waves + depth-2 pipeline pushed VGPR 16->68, occupancy
// 72%->25%, k_agg 43->54us. Resident-wave TLP beats software pipelining here.
// One node per 32-lane half, f8 lane owns a 16B uint4 chunk, eg in [0,4) is
// the edge subgroup (4 gathers in flight per lane), one pair per wave, LDS
// stat epilogue per block. VGPR ~16-32 -> 8 waves/SIMD.
// Streams (edges loads, Ab/emb/out stores) are NONTEMPORAL to keep L2 free
// for the Hs gather table (each row has ~2 refs per XCD -> hit-rate upside).
template <int DOUT, bool LSM>
__global__ __launch_bounds__(256) void k_agg(const unsigned int* __restrict__ Hs32,
                                             const int2* __restrict__ rowseg,
                                             const int* __restrict__ edges,
                                             const float* __restrict__ dinv,
                                             const float* __restrict__ bias,
                                             unsigned int* __restrict__ Ab32,
                                             float* __restrict__ emb,
                                             float* __restrict__ out,
                                             float* __restrict__ stats, int N) {
  constexpr int RD = DOUT / 2;       // dwords per row (32 or 20)
  constexpr int F8 = (RD + 3) / 4;   // active uint4 lanes per edge (8 or 5)
  int wid = (blockIdx.x * 256 + threadIdx.x) >> 6;
  int lane = threadIdx.x & 63;
  int hb = lane & 32;                // half base for shfl indices
  int lh = lane & 31;
  int f8 = lh & 7;
  int eg = lh >> 3;                  // edge subgroup 0..3 within half
  bool fok = f8 < F8;
  int node = wid * 2 + (lane >> 5);
  bool active = node < N;
  float aL[4], aH[4];
#pragma unroll
  for (int d = 0; d < 4; d++) { aL[d] = 0.f; aH[d] = 0.f; }
  int beg = 0, len = 0;
  if (active) {
    int2 sg = rowseg[node];
    beg = sg.x; len = sg.y - sg.x;
    if (eg == 0 && fok) {  // self-loop term
      uint4 u = *(const uint4*)(Hs32 + (unsigned)(node * RD) + 4 * f8);
      aL[0] = bf_lo(u.x); aH[0] = bf_hi(u.x);
      aL[1] = bf_lo(u.y); aH[1] = bf_hi(u.y);
      aL[2] = bf_lo(u.z); aH[2] = bf_hi(u.z);
      aL[3] = bf_lo(u.w); aH[3] = bf_hi(u.w);
    }
  }
  int lenmax = max(len, __shfl_xor(len, 32));  // wave-uniform batch count
#define ACC4(u)                                  \
  aL[0] += bf_lo(u.x); aH[0] += bf_hi(u.x);      \
  aL[1] += bf_lo(u.y); aH[1] += bf_hi(u.y);      \
  aL[2] += bf_lo(u.z); aH[2] += bf_hi(u.z);      \
  aL[3] += bf_lo(u.w); aH[3] += bf_hi(u.w);
  for (int off = 0; off < lenmax; off += 32) {
    int cnt = len - off;                      // per-half remaining (may be <=0)
    int bcnt = min(32, max(cnt, 0));
    // full-exec batch load; exhausted half clamps inside the (slack) allocation
    int srcv = __builtin_nontemporal_load(&edges[beg + off + (lh < bcnt ? lh : 0)]);
    int bmax = min(32, lenmax - off);         // wave-uniform
    for (int j = 0; j < bmax; j += 16) {
      int s0 = __shfl(srcv, hb + j + eg);
      int s1 = __shfl(srcv, hb + j + 4 + eg);
      int s2 = __shfl(srcv, hb + j + 8 + eg);
      int s3 = __shfl(srcv, hb + j + 12 + eg);
      bool p0 = fok && (j + eg) < bcnt;
      bool p1 = fok && (j + 4 + eg) < bcnt;
      bool p2 = fok && (j + 8 + eg) < bcnt;
      bool p3 = fok && (j + 12 + eg) < bcnt;
      uint4 u0, u1, u2, u3;
      if (p0) u0 = *(const uint4*)(Hs32 + (unsigned)(s0 * RD) + 4 * f8);
      if (p1) u1 = *(const uint4*)(Hs32 + (unsigned)(s1 * RD) + 4 * f8);
      if (p2) u2 = *(const uint4*)(Hs32 + (unsigned)(s2 * RD) + 4 * f8);
      if (p3) u3 = *(const uint4*)(Hs32 + (unsigned)(s3 * RD) + 4 * f8);
      if (p0) { ACC4(u0) }
      if (p1) { ACC4(u1) }
      if (p2) { ACC4(u2) }
      if (p3) { ACC4(u3) }
    }
  }
#undef ACC4
  // reduce across the 4 edge subgroups (stays inside each half): xor8 + xor16
#pragma unroll
  for (int d = 0; d < 4; d++) {
    aL[d] += __shfl_xor(aL[d], 8);  aH[d] += __shfl_xor(aH[d], 8);
    aL[d] += __shfl_xor(aL[d], 16); aH[d] += __shfl_xor(aH[d], 16);
  }
  float dn = 0.f;
  if (active) dn = dinv[node];
#pragma unroll
  for (int d = 0; d < 4; d++) { aL[d] *= dn; aH[d] *= dn; }
  if constexpr (!LSM) {
    if (active && eg == 0 && fok) {  // 8 lanes/half x 16B = full row, coalesced
      uint4 st;
      st.x = (unsigned int)f2bf(aL[0]) | ((unsigned int)f2bf(aH[0]) << 16);
      st.y = (unsigned int)f2bf(aL[1]) | ((unsigned int)f2bf(aH[1]) << 16);
      st.z = (unsigned int)f2bf(aL[2]) | ((unsigned int)f2bf(aH[2]) << 16);
      st.w = (unsigned int)f2bf(aL[3]) | ((unsigned int)f2bf(aH[3]) << 16);
      nts_u4(Ab32 + (unsigned)node * RD + 4 * f8, st);  // streaming out: nt
    }
    __shared__ float ls[8][64], ls2[8][64];
    int w2 = threadIdx.x >> 5;  // half-wave slot 0..7
    if (eg == 0) {
      int base = 8 * f8;
#pragma unroll
      for (int d = 0; d < 4; d++) {
        float v0 = (active && fok) ? aL[d] : 0.f;
        float v1 = (active && fok) ? aH[d] : 0.f;
        ls[w2][base + 2 * d] = v0;       ls[w2][base + 2 * d + 1] = v1;
        ls2[w2][base + 2 * d] = v0 * v0; ls2[w2][base + 2 * d + 1] = v1 * v1;
      }
    }
    __syncthreads();
    if (threadIdx.x < 64) {
      int t = threadIdx.x;
      float s = 0.f, s2 = 0.f;
#pragma unroll
      for (int w = 0; w < 8; w++) { s += ls[w][t]; s2 += ls2[w][t]; }
      int slot = blockIdx.x & (SLOTS - 1);
      atomicAdd(&stats[(size_t)slot * 128 + t], s);
      atomicAdd(&stats[(size_t)slot * 128 + 64 + t], s2);
    }
  } else {
    if (!active) return;  // wave-uniform (nodes padded to pair granularity)
    if (fok) {
      const float4 b0 = *(const float4*)(bias + 8 * f8);
      const float4 b1 = *(const float4*)(bias + 8 * f8 + 4);
      aL[0] += b0.x; aH[0] += b0.y; aL[1] += b0.z; aH[1] += b0.w;
      aL[2] += b1.x; aH[2] += b1.y; aL[3] += b1.z; aH[3] += b1.w;
    }
    float mx = fok ? fmaxf(fmaxf(fmaxf(aL[0], aH[0]), fmaxf(aL[1], aH[1])),
                           fmaxf(fmaxf(aL[2], aH[2]), fmaxf(aL[3], aH[3])))
                   : -INFINITY;
#pragma unroll
    for (int o = 1; o < 8; o <<= 1) mx = fmaxf(mx, __shfl_xor(mx, o));
    float ex = 0.f;
    if (fok) {
      ex = expf(aL[0] - mx) + expf(aH[0] - mx) + expf(aL[1] - mx) +
           expf(aH[1] - mx) + expf(aL[2] - mx) + expf(aH[2] - mx) +
           expf(aL[3] - mx) + expf(aH[3] - mx);
    }
#pragma unroll
    for (int o = 1; o < 8; o <<= 1) ex += __shfl_xor(ex, o);
    float lse = mx + logf(ex);
    if (eg == 0 && fok) {
      nts_f4(emb + (size_t)node * DOUT + 8 * f8,
             make_float4(aL[0], aH[0], aL[1], aH[1]));
      nts_f4(emb + (size_t)node * DOUT + 8 * f8 + 4,
             make_float4(aL[2], aH[2], aL[3], aH[3]));
      nts_f4(out + (size_t)node * DOUT + 8 * f8,
             make_float4(aL[0] - lse, aH[0] - lse, aL[1] - lse, aH[1] - lse));
      nts_f4(out + (size_t)node * DOUT + 8 * f8 + 4,
             make_float4(aL[2] - lse, aH[2] - lse, aL[3] - lse, aH[3] - lse));
    }
  }
}

extern "C" void kernel_launch(void* const* d_in, const int* in_sizes, int n_in,
                              void* d_out, int out_size, void* d_ws, size_t ws_size,
                              hipStream_t stream) {
  const float* x = (const float*)d_in[0];
  const int* ei = (const int*)d_in[1];
  const float* W1 = (const float*)d_in[2];
  // b1 = d_in[3], b2 = d_in[5]: cancel exactly inside BatchNorm (mean subtraction)
  const float* W2 = (const float*)d_in[4];
  const float* W3 = (const float*)d_in[6];
  const float* b3 = (const float*)d_in[7];
  const float* g1 = (const float*)d_in[8];
  const float* be1 = (const float*)d_in[9];
  const float* g2 = (const float*)d_in[10];
  const float* be2 = (const float*)d_in[11];

  int N = in_sizes[0] / 64;
  int E = in_sizes[1] / 2;
  const int* src = ei;
  const int* dst = ei + E;
  int NB = (N + 127) / 128;  // 128-node buckets
  float invN = 1.0f / (float)N;

  char* ws = (char*)d_ws;
  int* gcount = (int*)ws;                           // [NBMAX]   (zeroed)
  float* stats1 = (float*)(gcount + NBMAX);         // [SLOTS*128] (zeroed by gemm1)
  float* stats2 = stats1 + SLOTS * 128;             // [SLOTS*128] (zeroed by gemm2)
  float* dinv = stats2 + SLOTS * 128;               // [N]
  int2* rowseg = (int2*)(dinv + N);                 // [N] (beg,end)
  unsigned short* Hs =
      (unsigned short*)(((uintptr_t)(rowseg + N) + 15) & ~(uintptr_t)15);  // [N*64] bf16
  unsigned short* Ab = Hs + (size_t)N * 64;         // [N*64] bf16
  int* edges = (int*)(Ab + (size_t)N * 64);         // [NBMAX*BCAP] bucket-strided
  int* staging = (int*)Hs;  // [NBMAX*BCAP] aliases Hs/Ab (consumed before gemm1)

  float* out = (float*)d_out;
  float* emb = (float*)d_out + (size_t)N * 40;

  dim3 B(256);
  int gW = (N + 7) / 8;                   // two nodes per wave, 4 waves per block
  int gG64 = ((N + 255) / 256) * 2;       // column-split by block parity
  int gG40 = (N + 255) / 256;

  // ---- CSR build (+rowseg+dinv) ----
  hipMemsetAsync(gcount, 0, NBMAX * sizeof(int), stream);
  k_binA<<<(E + 4095) / 4096, B, 0, stream>>>(src, dst, gcount, staging, E, NB);
  k_binB<<<NB, B, 0, stream>>>(staging, gcount, rowseg, dinv, edges, N);

  // ---- layer 1 (zeroes stats1) ----
  k_gemm<64, false, false><<<gG64, B, 0, stream>>>(x, W1, nullptr, nullptr, nullptr,
                                                   dinv, Hs, stats1, N, invN);
  k_agg<64, false><<<gW, B, 0, stream>>>((const unsigned int*)Hs, rowseg, edges, dinv,
                                         nullptr, (unsigned int*)Ab, nullptr, nullptr,
                                         stats1, N);

  // ---- layer 2 (BN1 fold fused; zeroes stats2) ----
  k_gemm<64, true, true><<<gG64, B, 0, stream>>>(Ab, W2, stats1, g1, be1, dinv, Hs,
                                                 stats2, N, invN);
  k_agg<64, false><<<gW, B, 0, stream>>>((const unsigned int*)Hs, rowseg, edges, dinv,
                                         nullptr, (unsigned int*)Ab, nullptr, nullptr,
                                         stats2, N);

  // ---- layer 3 (BN2 fold fused): gemm -> agg(+b3) -> fused log_softmax ----
  k_gemm<40, true, true><<<gG40, B, 0, stream>>>(Ab, W3, stats2, g2, be2, dinv, Hs,
                                                 nullptr, N, invN);
  k_agg<40, true><<<gW, B, 0, stream>>>((const unsigned int*)Hs, rowseg, edges, dinv,
                                        b3, nullptr, emb, out, nullptr, N);
}

// Round 7
// 306.357 us; speedup vs baseline: 1.0940x; 1.0940x over previous
//
#include <hip/hip_runtime.h>
#include <hip/hip_bf16.h>
#include <math.h>
#include <stdint.h>

#define EPSV 1e-5f
#define BCAP 2560        // bucket capacity: mean 2048, sigma ~45 -> 11 sigma slack
#define NBMAX 1024       // >= ceil(N/128)
#define SLOTS 32         // BN-stat partial slots

static __device__ __forceinline__ float bf_lo(unsigned int u) {
  union { unsigned int i; float f; } v; v.i = u << 16; return v.f;
}
static __device__ __forceinline__ float bf_hi(unsigned int u) {
  union { unsigned int i; float f; } v; v.i = u & 0xffff0000u; return v.f;
}
static __device__ __forceinline__ unsigned short f2bf(float f) {
  union { float f; unsigned int i; } v; v.f = f;
  unsigned int r = v.i + 0x7fff + ((v.i >> 16) & 1);  // RTNE
  return (unsigned short)(r >> 16);
}

// ---------------- phase A: bin edges into 128-node buckets ----------------
__global__ __launch_bounds__(256) void k_binA(const int* __restrict__ src,
                                              const int* __restrict__ dst,
                                              int* __restrict__ gcount,
                                              int* __restrict__ staging, int E, int NB) {
  __shared__ int hist[NBMAX];
  __shared__ int gbase[NBMAX];
  int t = threadIdx.x;
  for (int b = t; b < NB; b += 256) hist[b] = 0;
  __syncthreads();
  int e0 = blockIdx.x * 4096;
  int sreg[16], dreg[16];
#pragma unroll
  for (int j = 0; j < 16; j++) {
    int e = e0 + j * 256 + t;
    if (e < E) {
      sreg[j] = src[e];
      dreg[j] = dst[e];
      atomicAdd(&hist[dreg[j] >> 7], 1);
    } else {
      dreg[j] = -1;
    }
  }
  __syncthreads();
  for (int b = t; b < NB; b += 256) {
    int c = hist[b];
    if (c) gbase[b] = b * BCAP + atomicAdd(&gcount[b], c);
    hist[b] = 0;  // reuse as local rank counter
  }
  __syncthreads();
#pragma unroll
  for (int j = 0; j < 16; j++) {
    if (dreg[j] >= 0) {
      int b = dreg[j] >> 7;
      int r = atomicAdd(&hist[b], 1);
      int pos = gbase[b] + r;
      if (pos < (b + 1) * BCAP)  // overflow guard (statistically impossible)
        staging[pos] = sreg[j] | ((dreg[j] & 127) << 20);
    }
  }
}

// ---------------- phase B: bucket -> CSR at STATIC base b*BCAP ----------------
__global__ __launch_bounds__(256) void k_binB(const int* __restrict__ staging,
                                              const int* __restrict__ gcount,
                                              int2* __restrict__ rowseg,
                                              float* __restrict__ dinv,
                                              int* __restrict__ edges, int N) {
  __shared__ int rec[BCAP];
  __shared__ int cnt[128], cur[128], scn[128];
  int b = blockIdx.x;
  int t = threadIdx.x;
  int lo = b * 128;
  int nn = min(128, N - lo);
  int c = min(gcount[b], BCAP);
  if (t < 128) cnt[t] = 0;
  __syncthreads();
  for (int r = t; r < c; r += 256) {
    int x = staging[b * BCAP + r];
    rec[r] = x;
    atomicAdd(&cnt[x >> 20], 1);
  }
  __syncthreads();
  if (t < 128) scn[t] = cnt[t];
  __syncthreads();
  for (int off = 1; off < 128; off <<= 1) {
    int tv = (t < 128 && t >= off) ? scn[t - off] : 0;
    __syncthreads();
    if (t < 128 && t >= off) scn[t] += tv;
    __syncthreads();
  }
  int base = b * BCAP;  // static bucket base
  if (t < 128) {
    int excl = (t == 0) ? 0 : scn[t - 1];
    cur[t] = excl;
    if (t < nn) {
      rowseg[lo + t] = make_int2(base + excl, base + excl + cnt[t]);
      dinv[lo + t] = rsqrtf((float)cnt[t] + 1.0f);  // +1 = self loop
    }
  }
  __syncthreads();
  for (int r = t; r < c; r += 256) {
    int x = rec[r];
    int pos = base + atomicAdd(&cur[x >> 20], 1);
    edges[pos] = x & 0xFFFFF;
  }
}

// ---------------- GEMM (+ fused BN fold) ----------------
// CSPL=2 for DOUT=64: columns split BY BLOCK PARITY (c0beg is an SGPR value ->
// W[k*DOUT+c0+j] stays wave-uniform -> scalar s_load broadcasts). R2 lesson:
// per-lane column offsets make W loads vector loads (127us disaster). R6 lesson:
// NO nontemporal hints anywhere — Ab and edges both have cross-kernel reuse;
// nt cost +28us total.
template <int DOUT, bool BFIN, bool FOLD>
__global__ __launch_bounds__(256) void k_gemm(const void* __restrict__ Xv,
                                              const float* __restrict__ W,
                                              const float* __restrict__ stats,
                                              const float* __restrict__ g,
                                              const float* __restrict__ be,
                                              const float* __restrict__ dinv,
                                              unsigned short* __restrict__ Hs,
                                              float* __restrict__ zstats, int N,
                                              float invN) {
  __shared__ float red[128];
  __shared__ float scale[64], shift[64], browS[64];
  int t = threadIdx.x;
  if (zstats && blockIdx.x == 0) {
    for (int i = t; i < SLOTS * 128; i += 256) zstats[i] = 0.f;
  }
  if constexpr (FOLD) {
    if (t < 128) {
      float s = 0.f;
      for (int b = 0; b < SLOTS; b++) s += stats[(size_t)b * 128 + t];
      red[t] = s;
    }
    __syncthreads();
    if (t < 64) {
      float mean = red[t] * invN;
      float var = red[64 + t] * invN - mean * mean;
      float sc = g[t] * rsqrtf(var + EPSV);
      scale[t] = sc;
      shift[t] = be[t] - mean * sc;
    }
    __syncthreads();
    if (t < DOUT) {
      float a = 0.f;
      for (int k = 0; k < 64; k++) a = fmaf(shift[k], W[k * DOUT + t], a);
      browS[t] = a;
    }
    __syncthreads();
  }
  constexpr int CSPL = (DOUT == 64) ? 2 : 1;
  int bid = blockIdx.x;
  int row = (CSPL == 2 ? (bid >> 1) : bid) * 256 + t;
  int c0beg = (CSPL == 2) ? ((bid & 1) * 32) : 0;  // SGPR -> wave-uniform
  int c0end = c0beg + DOUT / CSPL;
  if (row >= N) return;
  float xs[64];
  if constexpr (BFIN) {
    const uint4* xp = (const uint4*)((const unsigned short*)Xv + (size_t)row * 64);
#pragma unroll
    for (int i = 0; i < 8; i++) {
      uint4 u = xp[i];
      xs[i * 8 + 0] = bf_lo(u.x); xs[i * 8 + 1] = bf_hi(u.x);
      xs[i * 8 + 2] = bf_lo(u.y); xs[i * 8 + 3] = bf_hi(u.y);
      xs[i * 8 + 4] = bf_lo(u.z); xs[i * 8 + 5] = bf_hi(u.z);
      xs[i * 8 + 6] = bf_lo(u.w); xs[i * 8 + 7] = bf_hi(u.w);
    }
  } else {
    const float4* xp = (const float4*)((const float*)Xv + (size_t)row * 64);
#pragma unroll
    for (int i = 0; i < 16; i++) {
      float4 f = xp[i];
      xs[i * 4 + 0] = f.x; xs[i * 4 + 1] = f.y;
      xs[i * 4 + 2] = f.z; xs[i * 4 + 3] = f.w;
    }
  }
  if constexpr (FOLD) {
#pragma unroll
    for (int k = 0; k < 64; k++) xs[k] *= scale[k];  // LDS broadcast, conflict-free
  }
  float di = dinv[row];
#pragma unroll 1
  for (int c0 = c0beg; c0 < c0end; c0 += 8) {
    float acc[8];
#pragma unroll
    for (int j = 0; j < 8; j++) acc[j] = FOLD ? browS[c0 + j] : 0.0f;
#pragma unroll
    for (int k = 0; k < 64; k++) {
      float xk = xs[k];
#pragma unroll
      for (int j = 0; j < 8; j++) acc[j] = fmaf(xk, W[k * DOUT + c0 + j], acc[j]);
    }
    uint4 st;
    st.x = (unsigned int)f2bf(di * acc[0]) | ((unsigned int)f2bf(di * acc[1]) << 16);
    st.y = (unsigned int)f2bf(di * acc[2]) | ((unsigned int)f2bf(di * acc[3]) << 16);
    st.z = (unsigned int)f2bf(di * acc[4]) | ((unsigned int)f2bf(di * acc[5]) << 16);
    st.w = (unsigned int)f2bf(di * acc[6]) | ((unsigned int)f2bf(di * acc[7]) << 16);
    *(uint4*)(Hs + (size_t)row * DOUT + c0) = st;
  }
}

// ---------------- gather aggregation: TWO nodes per wave (R1 form) ----------------
// R3 lesson: persistent waves + depth-2 pipeline pushed VGPR 16->68, occupancy
// 72%->25%, k_agg 43->54us. Resident-wave TLP beats software pipelining here.
// One node per 32-lane half, f8 lane owns a 16B uint4 chunk, eg in [0,4) is
// the edge subgroup (4 gathers in flight per lane), one pair per wave, LDS
// stat epilogue per block. VGPR ~16-32 -> 8 waves/SIMD.
template <int DOUT, bool LSM>
__global__ __launch_bounds__(256) void k_agg(const unsigned int* __restrict__ Hs32,
                                             const int2* __restrict__ rowseg,
                                             const int* __restrict__ edges,
                                             const float* __restrict__ dinv,
                                             const float* __restrict__ bias,
                                             unsigned int* __restrict__ Ab32,
                                             float* __restrict__ emb,
                                             float* __restrict__ out,
                                             float* __restrict__ stats, int N) {
  constexpr int RD = DOUT / 2;       // dwords per row (32 or 20)
  constexpr int F8 = (RD + 3) / 4;   // active uint4 lanes per edge (8 or 5)
  int wid = (blockIdx.x * 256 + threadIdx.x) >> 6;
  int lane = threadIdx.x & 63;
  int hb = lane & 32;                // half base for shfl indices
  int lh = lane & 31;
  int f8 = lh & 7;
  int eg = lh >> 3;                  // edge subgroup 0..3 within half
  bool fok = f8 < F8;
  int node = wid * 2 + (lane >> 5);
  bool active = node < N;
  float aL[4], aH[4];
#pragma unroll
  for (int d = 0; d < 4; d++) { aL[d] = 0.f; aH[d] = 0.f; }
  int beg = 0, len = 0;
  if (active) {
    int2 sg = rowseg[node];
    beg = sg.x; len = sg.y - sg.x;
    if (eg == 0 && fok) {  // self-loop term
      uint4 u = *(const uint4*)(Hs32 + (unsigned)(node * RD) + 4 * f8);
      aL[0] = bf_lo(u.x); aH[0] = bf_hi(u.x);
      aL[1] = bf_lo(u.y); aH[1] = bf_hi(u.y);
      aL[2] = bf_lo(u.z); aH[2] = bf_hi(u.z);
      aL[3] = bf_lo(u.w); aH[3] = bf_hi(u.w);
    }
  }
  int lenmax = max(len, __shfl_xor(len, 32));  // wave-uniform batch count
#define ACC4(u)                                  \
  aL[0] += bf_lo(u.x); aH[0] += bf_hi(u.x);      \
  aL[1] += bf_lo(u.y); aH[1] += bf_hi(u.y);      \
  aL[2] += bf_lo(u.z); aH[2] += bf_hi(u.z);      \
  aL[3] += bf_lo(u.w); aH[3] += bf_hi(u.w);
  for (int off = 0; off < lenmax; off += 32) {
    int cnt = len - off;                      // per-half remaining (may be <=0)
    int bcnt = min(32, max(cnt, 0));
    // full-exec batch load; exhausted half clamps inside the (slack) allocation
    int srcv = edges[beg + off + (lh < bcnt ? lh : 0)];
    int bmax = min(32, lenmax - off);         // wave-uniform
    for (int j = 0; j < bmax; j += 16) {
      int s0 = __shfl(srcv, hb + j + eg);
      int s1 = __shfl(srcv, hb + j + 4 + eg);
      int s2 = __shfl(srcv, hb + j + 8 + eg);
      int s3 = __shfl(srcv, hb + j + 12 + eg);
      bool p0 = fok && (j + eg) < bcnt;
      bool p1 = fok && (j + 4 + eg) < bcnt;
      bool p2 = fok && (j + 8 + eg) < bcnt;
      bool p3 = fok && (j + 12 + eg) < bcnt;
      uint4 u0, u1, u2, u3;
      if (p0) u0 = *(const uint4*)(Hs32 + (unsigned)(s0 * RD) + 4 * f8);
      if (p1) u1 = *(const uint4*)(Hs32 + (unsigned)(s1 * RD) + 4 * f8);
      if (p2) u2 = *(const uint4*)(Hs32 + (unsigned)(s2 * RD) + 4 * f8);
      if (p3) u3 = *(const uint4*)(Hs32 + (unsigned)(s3 * RD) + 4 * f8);
      if (p0) { ACC4(u0) }
      if (p1) { ACC4(u1) }
      if (p2) { ACC4(u2) }
      if (p3) { ACC4(u3) }
    }
  }
#undef ACC4
  // reduce across the 4 edge subgroups (stays inside each half): xor8 + xor16
#pragma unroll
  for (int d = 0; d < 4; d++) {
    aL[d] += __shfl_xor(aL[d], 8);  aH[d] += __shfl_xor(aH[d], 8);
    aL[d] += __shfl_xor(aL[d], 16); aH[d] += __shfl_xor(aH[d], 16);
  }
  float dn = 0.f;
  if (active) dn = dinv[node];
#pragma unroll
  for (int d = 0; d < 4; d++) { aL[d] *= dn; aH[d] *= dn; }
  if constexpr (!LSM) {
    if (active && eg == 0 && fok) {  // 8 lanes/half x 16B = full row, coalesced
      uint4 st;
      st.x = (unsigned int)f2bf(aL[0]) | ((unsigned int)f2bf(aH[0]) << 16);
      st.y = (unsigned int)f2bf(aL[1]) | ((unsigned int)f2bf(aH[1]) << 16);
      st.z = (unsigned int)f2bf(aL[2]) | ((unsigned int)f2bf(aH[2]) << 16);
      st.w = (unsigned int)f2bf(aL[3]) | ((unsigned int)f2bf(aH[3]) << 16);
      *(uint4*)(Ab32 + (unsigned)node * RD + 4 * f8) = st;
    }
    __shared__ float ls[8][64], ls2[8][64];
    int w2 = threadIdx.x >> 5;  // half-wave slot 0..7
    if (eg == 0) {
      int base = 8 * f8;
#pragma unroll
      for (int d = 0; d < 4; d++) {
        float v0 = (active && fok) ? aL[d] : 0.f;
        float v1 = (active && fok) ? aH[d] : 0.f;
        ls[w2][base + 2 * d] = v0;       ls[w2][base + 2 * d + 1] = v1;
        ls2[w2][base + 2 * d] = v0 * v0; ls2[w2][base + 2 * d + 1] = v1 * v1;
      }
    }
    __syncthreads();
    if (threadIdx.x < 64) {
      int t = threadIdx.x;
      float s = 0.f, s2 = 0.f;
#pragma unroll
      for (int w = 0; w < 8; w++) { s += ls[w][t]; s2 += ls2[w][t]; }
      int slot = blockIdx.x & (SLOTS - 1);
      atomicAdd(&stats[(size_t)slot * 128 + t], s);
      atomicAdd(&stats[(size_t)slot * 128 + 64 + t], s2);
    }
  } else {
    if (!active) return;  // wave-uniform (nodes padded to pair granularity)
    if (fok) {
      const float4 b0 = *(const float4*)(bias + 8 * f8);
      const float4 b1 = *(const float4*)(bias + 8 * f8 + 4);
      aL[0] += b0.x; aH[0] += b0.y; aL[1] += b0.z; aH[1] += b0.w;
      aL[2] += b1.x; aH[2] += b1.y; aL[3] += b1.z; aH[3] += b1.w;
    }
    float mx = fok ? fmaxf(fmaxf(fmaxf(aL[0], aH[0]), fmaxf(aL[1], aH[1])),
                           fmaxf(fmaxf(aL[2], aH[2]), fmaxf(aL[3], aH[3])))
                   : -INFINITY;
#pragma unroll
    for (int o = 1; o < 8; o <<= 1) mx = fmaxf(mx, __shfl_xor(mx, o));
    float ex = 0.f;
    if (fok) {
      ex = expf(aL[0] - mx) + expf(aH[0] - mx) + expf(aL[1] - mx) +
           expf(aH[1] - mx) + expf(aL[2] - mx) + expf(aH[2] - mx) +
           expf(aL[3] - mx) + expf(aH[3] - mx);
    }
#pragma unroll
    for (int o = 1; o < 8; o <<= 1) ex += __shfl_xor(ex, o);
    float lse = mx + logf(ex);
    if (eg == 0 && fok) {
      *(float4*)(emb + (size_t)node * DOUT + 8 * f8) =
          make_float4(aL[0], aH[0], aL[1], aH[1]);
      *(float4*)(emb + (size_t)node * DOUT + 8 * f8 + 4) =
          make_float4(aL[2], aH[2], aL[3], aH[3]);
      *(float4*)(out + (size_t)node * DOUT + 8 * f8) =
          make_float4(aL[0] - lse, aH[0] - lse, aL[1] - lse, aH[1] - lse);
      *(float4*)(out + (size_t)node * DOUT + 8 * f8 + 4) =
          make_float4(aL[2] - lse, aH[2] - lse, aL[3] - lse, aH[3] - lse);
    }
  }
}

extern "C" void kernel_launch(void* const* d_in, const int* in_sizes, int n_in,
                              void* d_out, int out_size, void* d_ws, size_t ws_size,
                              hipStream_t stream) {
  const float* x = (const float*)d_in[0];
  const int* ei = (const int*)d_in[1];
  const float* W1 = (const float*)d_in[2];
  // b1 = d_in[3], b2 = d_in[5]: cancel exactly inside BatchNorm (mean subtraction)
  const float* W2 = (const float*)d_in[4];
  const float* W3 = (const float*)d_in[6];
  const float* b3 = (const float*)d_in[7];
  const float* g1 = (const float*)d_in[8];
  const float* be1 = (const float*)d_in[9];
  const float* g2 = (const float*)d_in[10];
  const float* be2 = (const float*)d_in[11];

  int N = in_sizes[0] / 64;
  int E = in_sizes[1] / 2;
  const int* src = ei;
  const int* dst = ei + E;
  int NB = (N + 127) / 128;  // 128-node buckets
  float invN = 1.0f / (float)N;

  char* ws = (char*)d_ws;
  int* gcount = (int*)ws;                           // [NBMAX]   (zeroed)
  float* stats1 = (float*)(gcount + NBMAX);         // [SLOTS*128] (zeroed by gemm1)
  float* stats2 = stats1 + SLOTS * 128;             // [SLOTS*128] (zeroed by gemm2)
  float* dinv = stats2 + SLOTS * 128;               // [N]
  int2* rowseg = (int2*)(dinv + N);                 // [N] (beg,end)
  unsigned short* Hs =
      (unsigned short*)(((uintptr_t)(rowseg + N) + 15) & ~(uintptr_t)15);  // [N*64] bf16
  unsigned short* Ab = Hs + (size_t)N * 64;         // [N*64] bf16
  int* edges = (int*)(Ab + (size_t)N * 64);         // [NBMAX*BCAP] bucket-strided
  int* staging = (int*)Hs;  // [NBMAX*BCAP] aliases Hs/Ab (consumed before gemm1)

  float* out = (float*)d_out;
  float* emb = (float*)d_out + (size_t)N * 40;

  dim3 B(256);
  int gW = (N + 7) / 8;                   // two nodes per wave, 4 waves per block
  int gG64 = ((N + 255) / 256) * 2;       // column-split by block parity
  int gG40 = (N + 255) / 256;

  // ---- CSR build (+rowseg+dinv) ----
  hipMemsetAsync(gcount, 0, NBMAX * sizeof(int), stream);
  k_binA<<<(E + 4095) / 4096, B, 0, stream>>>(src, dst, gcount, staging, E, NB);
  k_binB<<<NB, B, 0, stream>>>(staging, gcount, rowseg, dinv, edges, N);

  // ---- layer 1 (zeroes stats1) ----
  k_gemm<64, false, false><<<gG64, B, 0, stream>>>(x, W1, nullptr, nullptr, nullptr,
                                                   dinv, Hs, stats1, N, invN);
  k_agg<64, false><<<gW, B, 0, stream>>>((const unsigned int*)Hs, rowseg, edges, dinv,
                                         nullptr, (unsigned int*)Ab, nullptr, nullptr,
                                         stats1, N);

  // ---- layer 2 (BN1 fold fused; zeroes stats2) ----
  k_gemm<64, true, true><<<gG64, B, 0, stream>>>(Ab, W2, stats1, g1, be1, dinv, Hs,
                                                 stats2, N, invN);
  k_agg<64, false><<<gW, B, 0, stream>>>((const unsigned int*)Hs, rowseg, edges, dinv,
                                         nullptr, (unsigned int*)Ab, nullptr, nullptr,
                                         stats2, N);

  // ---- layer 3 (BN2 fold fused): gemm -> agg(+b3) -> fused log_softmax ----
  k_gemm<40, true, true><<<gG40, B, 0, stream>>>(Ab, W3, stats2, g2, be2, dinv, Hs,
                                                 nullptr, N, invN);
  k_agg<40, true><<<gW, B, 0, stream>>>((const unsigned int*)Hs, rowseg, edges, dinv,
                                        b3, nullptr, emb, out, nullptr, N);
}